// Round 10
// baseline (13.980 us; speedup 1.0000x reference)
//
#include <hip/hip_runtime.h>

// Problem constants (match reference)
#define BATCH     16
#define SEQ_N     1024
#define EMBED_DIM 256
#define NTILE     16     // n-values per block
#define STRIDEF   260    // LDS row stride in floats: 1KB row + 16B pad between rows

typedef float f32x4 __attribute__((ext_vector_type(4)));

// out[b][d][n] = embedding[seq[b][n]][d]
//
// Ledger (R1..R9): NT stores -1.8us; wave-uniform 1KB row loads mandatory
// (R6/R7 +6us); >=4 barrier domains/CU mandatory (R8 +7us); store chunk
// 64B vs 128B indistinguishable (R9).
//
// This round, single change vs R4: phase-1 via global_load_lds (direct
// HBM->LDS, no VGPR round-trip, no per-load waitcnt+ds_write). LDS dest is
// wave-uniform base + lane*16B (row-contiguous 1KB; pad sits BETWEEN rows).
//
// Block = (b, n-tile of 16), 512 threads. Grid 1024 -> 4 blocks/CU,
// 32 waves/CU, 4 barrier domains.
__global__ __launch_bounds__(512) void
embed_gather_transpose(const int* __restrict__ seq,
                       const float* __restrict__ emb,
                       float* __restrict__ out) {
    __shared__ float buf[NTILE * STRIDEF];   // 16.6 KB

    const int tid  = threadIdx.x;
    const int lane = tid & 63;

    const int b  = blockIdx.x >> 6;          // 64 tiles per batch
    const int n0 = (blockIdx.x & 63) << 4;   // *NTILE
    const int* seqb = seq + b * SEQ_N + n0;

    // ---- load phase: 16 rows, one 1KB global_load_lds burst per row ----
    // nn = i*8 + wave: wave-uniform. Lane l supplies gaddr row+l*16B; HW
    // writes LDS at (uniform base) + l*16B.
#pragma unroll
    for (int i = 0; i < 2; ++i) {
        const int flat = i * 512 + tid;
        const int nn   = flat >> 6;              // row in tile (wave-uniform)
        const int row  = seqb[nn];
        const float* gsrc = emb + (size_t)row * EMBED_DIM + lane * 4;
        __builtin_amdgcn_global_load_lds(
            (const __attribute__((address_space(1))) float*)gsrc,
            (__attribute__((address_space(3))) float*)&buf[nn * STRIDEF],
            16, 0, 0);
    }
    __syncthreads();   // drains vmcnt(0) + barrier: LDS tile complete

    // ---- store phase: 256 d x 4 f32x4 (16 n) = 1024, 2/thread ----
    // 4 consecutive lanes emit one contiguous 64B NT chunk per d.
    // Transpose read bank = (16q + d + 4k) mod 32 -> 2-way = free.
    float* outb = out + ((size_t)b * EMBED_DIM) * SEQ_N + n0;
#pragma unroll
    for (int i = 0; i < 2; ++i) {
        const int flat = i * 512 + tid;          // 0..1023
        const int d    = flat >> 2;              // 0..255
        const int q    = flat & 3;               // f32x4 index within 16-n chunk
        const int nn   = q << 2;
        f32x4 v;
        v.x = buf[(nn + 0) * STRIDEF + d];
        v.y = buf[(nn + 1) * STRIDEF + d];
        v.z = buf[(nn + 2) * STRIDEF + d];
        v.w = buf[(nn + 3) * STRIDEF + d];
        __builtin_nontemporal_store(
            v, reinterpret_cast<f32x4*>(outb + (size_t)d * SEQ_N) + q);
    }
}

extern "C" void kernel_launch(void* const* d_in, const int* in_sizes, int n_in,
                              void* d_out, int out_size, void* d_ws, size_t ws_size,
                              hipStream_t stream) {
    const int*   seq = (const int*)d_in[0];
    const float* emb = (const float*)d_in[1];
    float*       out = (float*)d_out;

    const int grid = BATCH * (SEQ_N / NTILE);  // 16 * 64 = 1024 blocks
    embed_gather_transpose<<<grid, 512, 0, stream>>>(seq, emb, out);
}

// Round 11
// 11.942 us; speedup vs baseline: 1.1706x; 1.1706x over previous
//
#include <hip/hip_runtime.h>

// Problem constants (match reference)
#define BATCH     16
#define SEQ_N     1024
#define EMBED_DIM 256
#define NTILE     32     // n-rows per tile -> store chunks are full 128B L2 lines
#define DHALF     128    // d-values stored per block

typedef float f32x4 __attribute__((ext_vector_type(4)));

// out[b][d][n] = embedding[seq[b][n]][d]
//
// Ledger (R1..R10): wave-uniform 1KB row loads mandatory (R6/R7 +6us);
// >=4 barrier domains/CU mandatory (R8 +7us); global_load_lds regresses
// (R10 +3.9us, vmcnt(0) barrier drain); 64B-chunk plain stores RFO-penalized
// (R5 +1.8us).
//
// THIS ROUND (single change vs R9): plain cached stores instead of NT, on
// full 128B-line chunks. Hypothesis: full-line writes skip RFO, land in
// L2/L3 write-back, and the 16MB output is absorbed by the 256MB L3 across
// graph replays -> steady-state HBM write traffic ~0 (NT forces 16MB/replay).
//
// Block = (b, n-tile of 32, d-half for STORES). Loads duplicate the full 32
// rows (wave-uniform 1KB bursts); stores cover 128 d as 128B-line chunks.
// Grid 1024 x 512 thr -> 4 blocks/CU = 32 waves/CU, 4 barrier domains.
// Pair-swizzle: blocks bid, bid+8 (same tile) land on the same XCD so the
// duplicate read L2-hits.
//
// LDS (32KB, no pad, XOR swizzle): element (r,d) at f4-slot r*64 +
// ((d>>2) ^ ((r>>2)&7)), word d&3.
//   write: r wave-uniform -> lane permutation -> conflict-free ds_write_b128
//   read:  per instr lanes (q in [0,8), dd in [0,8)): 2-way max = free
__global__ __launch_bounds__(512) void
embed_gather_transpose(const int* __restrict__ seq,
                       const float* __restrict__ emb,
                       float* __restrict__ out) {
    __shared__ f32x4 lds4[NTILE * 64];   // 32 KB
    const float* lds = reinterpret_cast<const float*>(lds4);

    // pair-swizzle: work p in [0,512), half h in {0,1}; bid=16m+8h+j -> p=8m+j
    const int bid = blockIdx.x;
    const int p   = ((bid >> 4) << 3) + (bid & 7);
    const int h   = (bid >> 3) & 1;

    const int b  = p >> 5;           // 16 batches
    const int n0 = (p & 31) << 5;    // 32 n-tiles of 32
    const int d0 = h << 7;           // d-half for stores

    const int* seqb = seq + b * SEQ_N + n0;

    // ---- load phase: 32 rows x 64 f32x4 = 2048, 4/thread ----
    // nn = flat>>6 wave-uniform; each wave-instr = one contiguous 1KB row.
#pragma unroll
    for (int i = 0; i < 4; ++i) {
        const int flat = i * 512 + threadIdx.x;   // 0..2047
        const int nn   = flat >> 6;               // row (wave-uniform)
        const int c4   = flat & 63;               // = lane
        const int row  = seqb[nn];
        lds4[nn * 64 + (c4 ^ ((nn >> 2) & 7))] =
            reinterpret_cast<const f32x4*>(emb + (size_t)row * EMBED_DIM)[c4];
    }
    __syncthreads();

    // ---- store phase: 128 d x 8 f32x4 (32 n) = 1024, 2/thread ----
    // 8 consecutive lanes emit one contiguous 128B FULL-LINE chunk per d,
    // via plain cached stores (write-back; no RFO on full lines — under test).
    float* outb = out + ((size_t)b * EMBED_DIM + d0) * SEQ_N + n0;
#pragma unroll
    for (int j = 0; j < 2; ++j) {
        const int flat = j * 512 + threadIdx.x;   // 0..1023
        const int dd   = flat >> 3;               // 0..127 (local d)
        const int d    = d0 + dd;                 // global d (for LDS col)
        const int q    = flat & 7;                // f4 index within 32-n chunk
        f32x4 v;
#pragma unroll
        for (int k = 0; k < 4; ++k) {
            const int r = 4 * q + k;              // row in tile
            v[k] = lds[r * 256 + 4 * ((d >> 2) ^ ((r >> 2) & 7)) + (d & 3)];
        }
        reinterpret_cast<f32x4*>(outb + (size_t)dd * SEQ_N)[q] = v;
    }
}

extern "C" void kernel_launch(void* const* d_in, const int* in_sizes, int n_in,
                              void* d_out, int out_size, void* d_ws, size_t ws_size,
                              hipStream_t stream) {
    const int*   seq = (const int*)d_in[0];
    const float* emb = (const float*)d_in[1];
    float*       out = (float*)d_out;

    const int grid = BATCH * (SEQ_N / NTILE) * (EMBED_DIM / DHALF);  // 1024
    embed_gather_transpose<<<grid, 512, 0, stream>>>(seq, emb, out);
}

// Round 12
// 10.097 us; speedup vs baseline: 1.3846x; 1.1828x over previous
//
#include <hip/hip_runtime.h>

// Problem constants (match reference)
#define BATCH     16
#define SEQ_N     1024
#define EMBED_DIM 256
#define NTILE     16
#define STRIDEF   260   // padded row stride (floats): transpose read 2-way = free

typedef float f32x4 __attribute__((ext_vector_type(4)));

// out[b][d][n] = embedding[seq[b][n]][d]
//
// Ledger: NT stores mandatory (+1.8us if cached, ANY width: R5/R11);
// store width 64B vs 128B irrelevant (R4/R9); wave-uniform 1KB row loads
// mandatory (R6/R7); global_load_lds regresses (R10); 2x read traffic free
// (R9) -> not BW-bound; 10.1us floor common to R4/R9.
//
// THIS ROUND: 2 tiles per block, double-buffered, software-pipelined —
// tile1's global-load latency hides under tile0's transpose+NT-store phase.
// Tests whether the 10.1us floor is the per-block serial phase chain
// (each block previously ran exactly one chain, no pipelining).
// Grid 512 x 512thr = 2 blocks/CU, 16 waves/CU, LDS 33KB/block.
__global__ __launch_bounds__(512) void
embed_gather_transpose(const int* __restrict__ seq,
                       const float* __restrict__ emb,
                       float* __restrict__ out) {
    __shared__ float bufA[NTILE * STRIDEF];   // 16.6 KB
    __shared__ float bufB[NTILE * STRIDEF];   // 16.6 KB

    const int tid = threadIdx.x;
    const int t0  = blockIdx.x << 1;          // first of 2 consecutive tiles
    const int b   = t0 >> 6;                  // 64 tiles per batch (both same b)
    const int n0  = (t0 & 63) << 4;

    const int* seqb = seq + b * SEQ_N + n0;
    float*     outb = out + ((size_t)b * EMBED_DIM) * SEQ_N + n0;

    // ---- tile0: global -> VGPR (wave-uniform 1KB row bursts) ----
    f32x4 va0, va1;
    {
        const int nn0 = tid >> 6,        c40 = tid & 63;
        const int nn1 = (512 + tid) >> 6, c41 = tid & 63;
        va0 = reinterpret_cast<const f32x4*>(emb + (size_t)seqb[nn0] * EMBED_DIM)[c40];
        va1 = reinterpret_cast<const f32x4*>(emb + (size_t)seqb[nn1] * EMBED_DIM)[c41];
        *reinterpret_cast<f32x4*>(&bufA[nn0 * STRIDEF + c40 * 4]) = va0;
        *reinterpret_cast<f32x4*>(&bufA[nn1 * STRIDEF + c41 * 4]) = va1;
    }
    __syncthreads();

    // ---- issue tile1 global loads (latency hides under store-phase A) ----
    f32x4 vb0, vb1;
    {
        const int nn0 = tid >> 6,         c40 = tid & 63;
        const int nn1 = (512 + tid) >> 6, c41 = tid & 63;
        vb0 = reinterpret_cast<const f32x4*>(emb + (size_t)seqb[16 + nn0] * EMBED_DIM)[c40];
        vb1 = reinterpret_cast<const f32x4*>(emb + (size_t)seqb[16 + nn1] * EMBED_DIM)[c41];
    }

    // ---- store-phase A: 256 d x 4 f32x4, NT 64B chunks ----
#pragma unroll
    for (int i = 0; i < 2; ++i) {
        const int flat = i * 512 + tid;
        const int d = flat >> 2, q = flat & 3, nn = q << 2;
        f32x4 v;
        v.x = bufA[(nn + 0) * STRIDEF + d];
        v.y = bufA[(nn + 1) * STRIDEF + d];
        v.z = bufA[(nn + 2) * STRIDEF + d];
        v.w = bufA[(nn + 3) * STRIDEF + d];
        __builtin_nontemporal_store(
            v, reinterpret_cast<f32x4*>(outb + (size_t)d * SEQ_N) + q);
    }

    // ---- tile1: VGPR -> LDS (compiler waits vmcnt for vb here) ----
    {
        const int nn0 = tid >> 6,         c40 = tid & 63;
        const int nn1 = (512 + tid) >> 6, c41 = tid & 63;
        *reinterpret_cast<f32x4*>(&bufB[nn0 * STRIDEF + c40 * 4]) = vb0;
        *reinterpret_cast<f32x4*>(&bufB[nn1 * STRIDEF + c41 * 4]) = vb1;
    }
    __syncthreads();

    // ---- store-phase B ----
    float* outb1 = outb + 16;
#pragma unroll
    for (int i = 0; i < 2; ++i) {
        const int flat = i * 512 + tid;
        const int d = flat >> 2, q = flat & 3, nn = q << 2;
        f32x4 v;
        v.x = bufB[(nn + 0) * STRIDEF + d];
        v.y = bufB[(nn + 1) * STRIDEF + d];
        v.z = bufB[(nn + 2) * STRIDEF + d];
        v.w = bufB[(nn + 3) * STRIDEF + d];
        __builtin_nontemporal_store(
            v, reinterpret_cast<f32x4*>(outb1 + (size_t)d * SEQ_N) + q);
    }
}

extern "C" void kernel_launch(void* const* d_in, const int* in_sizes, int n_in,
                              void* d_out, int out_size, void* d_ws, size_t ws_size,
                              hipStream_t stream) {
    const int*   seq = (const int*)d_in[0];
    const float* emb = (const float*)d_in[1];
    float*       out = (float*)d_out;

    const int grid = BATCH * (SEQ_N / NTILE) / 2;  // 512 blocks, 2 tiles each
    embed_gather_transpose<<<grid, 512, 0, stream>>>(seq, emb, out);
}